// Round 11
// baseline (308.083 us; speedup 1.0000x reference)
//
#include <hip/hip_runtime.h>
#include <hip/hip_bf16.h>

// Problem constants
#define BATCH 4
#define SEQ   2048
#define DIM   1024      // D = H*HDIM
#define NHEAD 16
#define HDIM  64
#define EPS_LN 1e-5f
// 1/sqrt(64) * log2(e): folded into Q projection so attention can use exp2
#define QSCALE 0.18033688011112042f

typedef __attribute__((ext_vector_type(8))) short short8;   // 8 bf16 = 4 VGPR
typedef __attribute__((ext_vector_type(4))) float f32x4;    // MFMA acc
typedef __attribute__((ext_vector_type(4))) unsigned uint32x4;

__device__ __forceinline__ unsigned short f2bf(float x) {
    __hip_bfloat16 h = __float2bfloat16(x);
    return *reinterpret_cast<unsigned short*>(&h);
}
__device__ __forceinline__ unsigned int pack2bf(float a, float b) {
    __hip_bfloat162 h = __float22bfloat162_rn(float2{a, b});
    return *reinterpret_cast<unsigned int*>(&h);
}

// gfx950 register-pair lane swaps (both operands are read-modify-write).
// v_permlane32_swap_b32: vdst[32:63] <-> src[0:31]
// v_permlane16_swap_b32: rows 1,3 (lanes 16-31,48-63) of vdst <-> rows 0,2 of src
__device__ __forceinline__ void pl32_swap(unsigned& a, unsigned& b) {
    asm("v_permlane32_swap_b32 %0, %1" : "+v"(a), "+v"(b));
}
__device__ __forceinline__ void pl16_swap(unsigned& a, unsigned& b) {
    asm("v_permlane16_swap_b32 %0, %1" : "+v"(a), "+v"(b));
}

// async 16B global -> LDS (per-lane gptr; LDS dest must be wave-uniform-base + lane*16)
__device__ __forceinline__ void gl_lds16(const void* g, void* l) {
    __builtin_amdgcn_global_load_lds(
        (const __attribute__((address_space(1))) unsigned int*)g,
        (__attribute__((address_space(3))) unsigned int*)l,
        16, 0, 0);
}

// ---------------- prep: 4 weight transposes (z=0..3) + queries convert (z=4) ----------------
__global__ __launch_bounds__(256) void prep_kernel(const float* __restrict__ W0,
                                                   const float* __restrict__ W1,
                                                   const float* __restrict__ W2,
                                                   const float* __restrict__ W3,
                                                   const float* __restrict__ queries,
                                                   unsigned short* __restrict__ Wqkvt,
                                                   unsigned short* __restrict__ Wot,
                                                   unsigned short* __restrict__ qout)
{
    const int z = blockIdx.z;
    const int t = threadIdx.x;

    if (z == 4) {
        // bulk fp32 -> bf16 convert of queries
        const int nthr = 16 * 16 * 256;            // 65536
        int i = (blockIdx.y * 16 + blockIdx.x) * 256 + t;
        for (int it = 0; it < (BATCH * SEQ * DIM / 4) / nthr; it++, i += nthr) {
            float4 v = ((const float4*)queries)[i];
            ushort4 u;
            u.x = f2bf(v.x); u.y = f2bf(v.y); u.z = f2bf(v.z); u.w = f2bf(v.w);
            ((ushort4*)qout)[i] = u;
        }
        return;
    }

    __shared__ float Ts[64][65];
    const float* W = (z == 0) ? W0 : (z == 1) ? W1 : (z == 2) ? W2 : W3;
    unsigned short* Wt = (z == 3) ? Wot : (Wqkvt + (size_t)z * DIM * DIM);

    const int k0 = blockIdx.y * 64, n0 = blockIdx.x * 64;
    const int lr = t >> 2, lq = t & 3;

#pragma unroll
    for (int i = 0; i < 4; i++) {
        float4 v = *(const float4*)(W + (size_t)(k0 + lr) * DIM + n0 + (lq * 4 + i) * 4);
        Ts[lr][(lq * 4 + i) * 4 + 0] = v.x;
        Ts[lr][(lq * 4 + i) * 4 + 1] = v.y;
        Ts[lr][(lq * 4 + i) * 4 + 2] = v.z;
        Ts[lr][(lq * 4 + i) * 4 + 3] = v.w;
    }
    __syncthreads();
#pragma unroll
    for (int i = 0; i < 4; i++) {
        const int c = lq * 16 + i * 4;
        ushort4 u;
        u.x = f2bf(Ts[c + 0][lr]);
        u.y = f2bf(Ts[c + 1][lr]);
        u.z = f2bf(Ts[c + 2][lr]);
        u.w = f2bf(Ts[c + 3][lr]);
        *(ushort4*)(Wt + (size_t)(n0 + lr) * DIM + k0 + c) = u;
    }
}

// ---------------- fused QKV GEMM: [8192,1024] @ [3072,1024]^T ----------------
// sector 0: Qbf natural bf16, (acc+bq)*QSCALE
// sector 1: Kbf natural bf16, acc+bk
// sector 2: Vtb transposed-per-head: Vt[b][h][d][l], acc+bv
__global__ __launch_bounds__(256) void gemm_qkv(const unsigned short* __restrict__ A,
                                                const unsigned short* __restrict__ Bt,
                                                const float* __restrict__ bq,
                                                const float* __restrict__ bk,
                                                const float* __restrict__ bv,
                                                unsigned short* __restrict__ Qbf,
                                                unsigned short* __restrict__ Kbf,
                                                unsigned short* __restrict__ Vtb)
{
    __shared__ __attribute__((aligned(16))) unsigned short As[128 * 32];
    __shared__ __attribute__((aligned(16))) unsigned short Bs[128 * 32];

    const int tid = threadIdx.x;
    const int w = tid >> 6, lane = tid & 63;
    const int col = lane & 15, quad = lane >> 4;
    const int wm = (w >> 1) * 64, wn = (w & 1) * 64;
    const int m0 = blockIdx.y * 128, n0 = blockIdx.x * 128;

    f32x4 acc[4][4] = {};
    const int srow = tid >> 2, sc4 = tid & 3;

    for (int k0 = 0; k0 < DIM; k0 += 32) {
        __syncthreads();
#pragma unroll
        for (int it = 0; it < 2; it++) {
            gl_lds16(A  + (size_t)(m0 + srow + it * 64) * DIM + k0 + sc4 * 8,
                     (char*)As + w * 1024 + it * 4096);
            gl_lds16(Bt + (size_t)(n0 + srow + it * 64) * DIM + k0 + sc4 * 8,
                     (char*)Bs + w * 1024 + it * 4096);
        }
        __syncthreads();

        short8 af[4], bf[4];
#pragma unroll
        for (int mt = 0; mt < 4; mt++) af[mt] = *(short8*)&As[(wm + mt * 16 + col) * 32 + quad * 8];
#pragma unroll
        for (int nt = 0; nt < 4; nt++) bf[nt] = *(short8*)&Bs[(wn + nt * 16 + col) * 32 + quad * 8];

#pragma unroll
        for (int mt = 0; mt < 4; mt++)
#pragma unroll
            for (int nt = 0; nt < 4; nt++)
                acc[mt][nt] = __builtin_amdgcn_mfma_f32_16x16x32_bf16(af[mt], bf[nt], acc[mt][nt], 0, 0, 0);
    }

    const int sector = n0 >> 10;   // block never straddles (1024 % 128 == 0)
    const float* bias = (sector == 0) ? bq : (sector == 1) ? bk : bv;

#pragma unroll
    for (int nt = 0; nt < 4; nt++) {
        const int n = n0 + wn + nt * 16 + col;
        const int nloc = n - (sector << 10);
        const float bvv = bias[nloc];
#pragma unroll
        for (int mt = 0; mt < 4; mt++) {
            const int mbase = m0 + wm + mt * 16 + quad * 4;
            if (sector == 0) {
#pragma unroll
                for (int r = 0; r < 4; r++)
                    Qbf[(size_t)(mbase + r) * DIM + nloc] = f2bf((acc[mt][nt][r] + bvv) * QSCALE);
            } else if (sector == 1) {
#pragma unroll
                for (int r = 0; r < 4; r++)
                    Kbf[(size_t)(mbase + r) * DIM + nloc] = f2bf(acc[mt][nt][r] + bvv);
            } else {
                const int h = nloc >> 6, d = nloc & 63;
                const int b = mbase >> 11, l = mbase & 2047;
                ushort4 u;
                u.x = f2bf(acc[mt][nt][0] + bvv);
                u.y = f2bf(acc[mt][nt][1] + bvv);
                u.z = f2bf(acc[mt][nt][2] + bvv);
                u.w = f2bf(acc[mt][nt][3] + bvv);
                *(ushort4*)(Vtb + ((size_t)((b * NHEAD + h) * HDIM + d)) * SEQ + l) = u;
            }
        }
    }
}

// ---------------- out-proj GEMM: fp32 out = A @ Wot^T + bo + resid ----------------
__global__ __launch_bounds__(256) void gemm_out(const unsigned short* __restrict__ A,
                                                const unsigned short* __restrict__ Bt,
                                                const float* __restrict__ bias,
                                                const float* __restrict__ resid,
                                                float* __restrict__ Cout)
{
    __shared__ __attribute__((aligned(16))) unsigned short As[128 * 32];
    __shared__ __attribute__((aligned(16))) unsigned short Bs[128 * 32];

    const int tid = threadIdx.x;
    const int w = tid >> 6, lane = tid & 63;
    const int col = lane & 15, quad = lane >> 4;
    const int wm = (w >> 1) * 64, wn = (w & 1) * 64;
    const int m0 = blockIdx.y * 128, n0 = blockIdx.x * 128;

    f32x4 acc[4][4] = {};
    const int srow = tid >> 2, sc4 = tid & 3;

    for (int k0 = 0; k0 < DIM; k0 += 32) {
        __syncthreads();
#pragma unroll
        for (int it = 0; it < 2; it++) {
            gl_lds16(A  + (size_t)(m0 + srow + it * 64) * DIM + k0 + sc4 * 8,
                     (char*)As + w * 1024 + it * 4096);
            gl_lds16(Bt + (size_t)(n0 + srow + it * 64) * DIM + k0 + sc4 * 8,
                     (char*)Bs + w * 1024 + it * 4096);
        }
        __syncthreads();

        short8 af[4], bf[4];
#pragma unroll
        for (int mt = 0; mt < 4; mt++) af[mt] = *(short8*)&As[(wm + mt * 16 + col) * 32 + quad * 8];
#pragma unroll
        for (int nt = 0; nt < 4; nt++) bf[nt] = *(short8*)&Bs[(wn + nt * 16 + col) * 32 + quad * 8];

#pragma unroll
        for (int mt = 0; mt < 4; mt++)
#pragma unroll
            for (int nt = 0; nt < 4; nt++)
                acc[mt][nt] = __builtin_amdgcn_mfma_f32_16x16x32_bf16(af[mt], bf[nt], acc[mt][nt], 0, 0, 0);
    }

#pragma unroll
    for (int nt = 0; nt < 4; nt++) {
        const int n = n0 + wn + nt * 16 + col;
        const float bvv = bias[n];
#pragma unroll
        for (int mt = 0; mt < 4; mt++) {
            const int mbase = m0 + wm + mt * 16 + quad * 4;
#pragma unroll
            for (int r = 0; r < 4; r++) {
                const size_t off = (size_t)(mbase + r) * DIM + n;
                Cout[off] = acc[mt][nt][r] + bvv + resid[off];
            }
        }
    }
}

// ---------------- MFMA flash attention v18: v17 body, key-split 2-way, 1024 blocks ----------------
// v17 (91.2us champion) counters: occupancy 35% (grid 512 = 2 blocks/CU caps
// at 16 waves/CU while VGPR=60 would allow 32), VALU 47us top pipe, wall 2x
// max pipe -> overlap-limited. v18 halves per-wave work and doubles blocks:
// wave (qw 0..3, kw 0..1) does 32 q x 32 keys (kw half of each tile).
// Per-CU totals unchanged; grid 1024 -> 4 blocks/CU x 8 waves -> up to 32
// waves/CU. This is v15's key-split done right:
//  - 16x16 body (o = 32 regs, not v15's 64; conflict-free ca/cb reads)
//  - merge exchange laid out FRAGMENT-major (buf[frag][lane]: 64 consecutive
//    float4 = contiguous 1KB per op, conflict-free) vs v15's lane-major
//    stride-128B (4-way conflicts, 9.5e6)
//  - merge once per block through the dead K/V LDS (+1 barrier)
// Plain-exp2 softmax (no running max) -> key-half partials merge by addition.
__global__ __launch_bounds__(512) void attn_mfma(const unsigned short* __restrict__ Qb,
                                                 const unsigned short* __restrict__ Kb,
                                                 const unsigned short* __restrict__ Vt,
                                                 unsigned short* __restrict__ Ob)
{
    __shared__ __attribute__((aligned(16))) unsigned short Ks[2 * 64 * 64];  // [buf][key][d'] swizzled
    __shared__ __attribute__((aligned(16))) unsigned short Vs[2 * 64 * 64];  // [buf][d][key'] swizzled
    __shared__ float DsX[128];                                               // denom partials (kw=1)

    const int tid = threadIdx.x;
    const int w = tid >> 6, lane = tid & 63;     // w = 0..7
    const int qw = w & 3, kw = w >> 2;
    const int col = lane & 15, quad = lane >> 4;
    const int cs  = col & 7;            // read-side swizzle key (row&7 == col&7 for all frag rows)
    const int ca  = quad ^ cs;          // chunk holding halfs quad*8 .. +7      (keys/d 0..31)
    const int cb  = (quad ^ 4) ^ cs;    // chunk holding halfs quad*8+32 .. +39  (keys/d 32..63)

    const int bh  = blockIdx.x & 63;   // (b,h) fastest -> q-blocks of one head share an XCD
    const int qt_ = blockIdx.x >> 6;   // 0..15 (q-tile of 128)
    const int b   = bh >> 4;
    const int h   = bh & 15;

    const int q0 = qt_ * 128 + qw * 32;   // 32 q-rows per qw group

    // Q B-fragments (two 16-row tiles per wave)
    short8 qf[2][2];
#pragma unroll
    for (int qt = 0; qt < 2; qt++) {
        const size_t base = ((size_t)(b * SEQ) + q0 + qt * 16 + col) * DIM + h * HDIM + quad * 8;
        qf[qt][0] = *(const short8*)(Qb + base);
        qf[qt][1] = *(const short8*)(Qb + base + 32);
    }

    // ones A-fragment (row 0 = key-sum of P)
    short8 onesf;
    {
        const short v = (col == 0) ? (short)0x3F80 : (short)0;
        onesf = short8{v, v, v, v, v, v, v, v};
    }

    f32x4 o[4][2] = {};
    f32x4 od[2]   = {};

    const size_t kbase0 = ((size_t)(b * SEQ)) * DIM + h * HDIM;
    const size_t vbase0 = ((size_t)((b * NHEAD + h) * HDIM)) * SEQ;

    // DMA staging: wave w stages rows w*8 .. w*8+7 of K and of V (1 instr each).
    // Linear LDS dest, XOR-swizzled global source chunk (involution).
    const int lr  = lane >> 3;              // row-within-8 (== row&7)
    const int swc = (lane & 7) ^ lr;        // swizzled source chunk

    // prologue: DMA tile 0 into buf 0
    {
        const int row = w * 8 + lr;
        gl_lds16(Kb + kbase0 + (size_t)row * DIM + swc * 8, (char*)Ks + w * 1024);
        gl_lds16(Vt + vbase0 + (size_t)row * SEQ + swc * 8, (char*)Vs + w * 1024);
    }
    __syncthreads();

    for (int kt = 0; kt < SEQ / 64; kt++) {
        const int cur = kt & 1, nxt = cur ^ 1;
        const unsigned short* Ksb = Ks + cur * 4096;
        const unsigned short* Vsb = Vs + cur * 4096;

        // issue next tile's DMA now; latency hides under this tile's compute
        if (kt + 1 < SEQ / 64) {
            const int row = w * 8 + lr;
            gl_lds16(Kb + kbase0 + (size_t)((kt + 1) * 64 + row) * DIM + swc * 8,
                     (char*)Ks + nxt * 8192 + w * 1024);
            gl_lds16(Vt + vbase0 + (size_t)row * SEQ + (kt + 1) * 64 + swc * 8,
                     (char*)Vs + nxt * 8192 + w * 1024);
        }

        // S^T (own 32-key half) = K @ Q^T ; P = 2^S ; reshape to PV B-fragment.
        short8 pf[2];
        {
            const int nte = kw * 2 + 0, nto = kw * 2 + 1;
            short8 kfe0 = *(short8*)&Ksb[(nte * 16 + col) * 64 + ca * 8];
            short8 kfe1 = *(short8*)&Ksb[(nte * 16 + col) * 64 + cb * 8];
            short8 kfo0 = *(short8*)&Ksb[(nto * 16 + col) * 64 + ca * 8];
            short8 kfo1 = *(short8*)&Ksb[(nto * 16 + col) * 64 + cb * 8];
#pragma unroll
            for (int qt = 0; qt < 2; qt++) {
                f32x4 se = {};
                se = __builtin_amdgcn_mfma_f32_16x16x32_bf16(kfe0, qf[qt][0], se, 0, 0, 0);
                se = __builtin_amdgcn_mfma_f32_16x16x32_bf16(kfe1, qf[qt][1], se, 0, 0, 0);
                f32x4 so = {};
                so = __builtin_amdgcn_mfma_f32_16x16x32_bf16(kfo0, qf[qt][0], so, 0, 0, 0);
                so = __builtin_amdgcn_mfma_f32_16x16x32_bf16(kfo1, qf[qt][1], so, 0, 0, 0);

                unsigned a0 = pack2bf(__builtin_amdgcn_exp2f(se[0]), __builtin_amdgcn_exp2f(se[1]));
                unsigned b0 = pack2bf(__builtin_amdgcn_exp2f(se[2]), __builtin_amdgcn_exp2f(se[3]));
                unsigned a1 = pack2bf(__builtin_amdgcn_exp2f(so[0]), __builtin_amdgcn_exp2f(so[1]));
                unsigned b1 = pack2bf(__builtin_amdgcn_exp2f(so[2]), __builtin_amdgcn_exp2f(so[3]));

                pl32_swap(a0, a1);   // pair even/odd nt across lane halves
                pl32_swap(b0, b1);
                pl16_swap(a0, a1);   // quad exchange 0<->1, 2<->3
                pl16_swap(b0, b1);

                uint32x4 cv = {a0, b0, a1, b1};
                pf[qt] = __builtin_bit_cast(short8, cv);
            }
        }

        __builtin_amdgcn_s_setprio(1);
        // denominator rows (ones A-fragment MFMA; covers own 32 keys)
#pragma unroll
        for (int qt = 0; qt < 2; qt++)
            od[qt] = __builtin_amdgcn_mfma_f32_16x16x32_bf16(onesf, pf[qt], od[qt], 0, 0, 0);

        // O^T += V^T[d][own key half] @ P^T (V-fragment read once, reused for both qt)
#pragma unroll
        for (int mt = 0; mt < 4; mt++) {
            short8 vf = *(short8*)&Vsb[(mt * 16 + col) * 64 + (kw ? cb : ca) * 8];
#pragma unroll
            for (int qt = 0; qt < 2; qt++)
                o[mt][qt] = __builtin_amdgcn_mfma_f32_16x16x32_bf16(vf, pf[qt], o[mt][qt], 0, 0, 0);
        }
        __builtin_amdgcn_s_setprio(0);

        // drains vmcnt (next tile's DMA landed) + lgkmcnt (this tile's reads done)
        __syncthreads();
    }

    // ---- cross-wave merge (kw pair), fragment-major conflict-free layout ----
    // kw=1 ships O partials + den through the dead K/V LDS; kw=0 merges.
    // Region per qw: 8 fragments x 64 lanes x 16B = 8KB. qw0/1 -> Ks, qw2/3 -> Vs.
    float4* xbuf = (qw & 2) ? (float4*)Vs : (float4*)Ks;
    const int xbase = (qw & 1) * 512;           // in float4 units
    if (kw == 1) {
#pragma unroll
        for (int mt = 0; mt < 4; mt++)
#pragma unroll
            for (int qt = 0; qt < 2; qt++)
                xbuf[xbase + (mt * 2 + qt) * 64 + lane] = __builtin_bit_cast(float4, o[mt][qt]);
        if (quad == 0) {
            DsX[(qw * 2 + 0) * 16 + col] = od[0][0];
            DsX[(qw * 2 + 1) * 16 + col] = od[1][0];
        }
    }
    __syncthreads();
    if (kw == 0) {
#pragma unroll
        for (int qt = 0; qt < 2; qt++) {
            const float den = __shfl(od[qt][0], col) + DsX[(qw * 2 + qt) * 16 + col];
            const float inv = 1.f / den;
            const size_t rowoff = ((size_t)(b * SEQ) + q0 + qt * 16 + col) * DIM + h * HDIM;
#pragma unroll
            for (int mt = 0; mt < 4; mt++) {
                const float4 p = xbuf[xbase + (mt * 2 + qt) * 64 + lane];
                ushort4 u;
                u.x = f2bf((o[mt][qt][0] + p.x) * inv);
                u.y = f2bf((o[mt][qt][1] + p.y) * inv);
                u.z = f2bf((o[mt][qt][2] + p.z) * inv);
                u.w = f2bf((o[mt][qt][3] + p.w) * inv);
                *(ushort4*)(Ob + rowoff + mt * 16 + quad * 4) = u;
            }
        }
    }
}

// ---------------- LayerNorm (in-place on d_out) ----------------
__global__ __launch_bounds__(256) void layernorm_kernel(float* __restrict__ res,
                                                        const float* __restrict__ gamma,
                                                        const float* __restrict__ beta)
{
    const int tid = threadIdx.x;
    const int row = blockIdx.x;
    float4 xv = ((const float4*)(res + (size_t)row * DIM))[tid];

    float s  = xv.x + xv.y + xv.z + xv.w;
    float sq = xv.x * xv.x + xv.y * xv.y + xv.z * xv.z + xv.w * xv.w;
#pragma unroll
    for (int off = 32; off; off >>= 1) {
        s  += __shfl_xor(s, off);
        sq += __shfl_xor(sq, off);
    }
    __shared__ float sm[8];
    const int w = tid >> 6, lane = tid & 63;
    if (lane == 0) { sm[w] = s; sm[4 + w] = sq; }
    __syncthreads();
    const float st  = sm[0] + sm[1] + sm[2] + sm[3];
    const float sqt = sm[4] + sm[5] + sm[6] + sm[7];
    const float mu   = st * (1.f / DIM);
    const float var  = sqt * (1.f / DIM) - mu * mu;
    const float rstd = rsqrtf(var + EPS_LN);

    float4 g  = ((const float4*)gamma)[tid];
    float4 be = ((const float4*)beta)[tid];
    float4 o;
    o.x = (xv.x - mu) * rstd * g.x + be.x;
    o.y = (xv.y - mu) * rstd * g.y + be.y;
    o.z = (xv.z - mu) * rstd * g.z + be.z;
    o.w = (xv.w - mu) * rstd * g.w + be.w;
    ((float4*)(res + (size_t)row * DIM))[tid] = o;
}

// ---------------- launch ----------------
extern "C" void kernel_launch(void* const* d_in, const int* in_sizes, int n_in,
                              void* d_out, int out_size, void* d_ws, size_t ws_size,
                              hipStream_t stream)
{
    const float* queries = (const float*)d_in[0];
    const float* Wq = (const float*)d_in[1];
    const float* bq = (const float*)d_in[2];
    const float* Wk = (const float*)d_in[3];
    const float* bk = (const float*)d_in[4];
    const float* Wv = (const float*)d_in[5];
    const float* bv = (const float*)d_in[6];
    const float* Wo = (const float*)d_in[7];
    const float* bo = (const float*)d_in[8];
    const float* gamma = (const float*)d_in[9];
    const float* beta  = (const float*)d_in[10];
    float* outp = (float*)d_out;

    const int M = BATCH * SEQ;                    // 8192
    const size_t BUF = (size_t)M * DIM;
    const size_t WSZ = (size_t)DIM * DIM;

    unsigned short* w0  = (unsigned short*)d_ws;
    unsigned short* qin = w0;                     // bf16 queries; later: attention output
    unsigned short* Qbf = w0 + BUF;
    unsigned short* Kbf = w0 + 2 * BUF;
    unsigned short* Vtb = w0 + 3 * BUF;
    unsigned short* Wqkvt = w0 + 4 * BUF;         // [3072][1024]
    unsigned short* Wot   = Wqkvt + 3 * WSZ;
    unsigned short* Obf = qin;                    // reuse

    dim3 blk(256);

    // z=0..3: weight transposes; z=4: queries fp32->bf16
    dim3 pgrid(DIM / 64, DIM / 64, 5);
    prep_kernel<<<pgrid, blk, 0, stream>>>(Wq, Wk, Wv, Wo, queries, Wqkvt, Wot, qin);

    dim3 qkvgrid(3 * DIM / 128, M / 128);         // (24, 64) = 1536 blocks
    gemm_qkv<<<qkvgrid, blk, 0, stream>>>(qin, Wqkvt, bq, bk, bv, Qbf, Kbf, Vtb);

    // 1024 blocks x 512 threads: swizzled decode (bh = idx & 63, qt = idx >> 6)
    attn_mfma<<<BATCH * NHEAD * (SEQ / 128), dim3(512), 0, stream>>>(Qbf, Kbf, Vtb, Obf);

    dim3 ogrid(DIM / 128, M / 128);               // (8, 64)
    gemm_out<<<ogrid, blk, 0, stream>>>(Obf, Wot, bo, queries, outp);

    layernorm_kernel<<<M, blk, 0, stream>>>(outp, gamma, beta);
}

// Round 13
// 293.002 us; speedup vs baseline: 1.0515x; 1.0515x over previous
//
#include <hip/hip_runtime.h>
#include <hip/hip_bf16.h>

// Problem constants
#define BATCH 4
#define SEQ   2048
#define DIM   1024      // D = H*HDIM
#define NHEAD 16
#define HDIM  64
#define EPS_LN 1e-5f
// 1/sqrt(64) * log2(e): folded into Q projection so attention can use exp2
#define QSCALE 0.18033688011112042f

typedef __attribute__((ext_vector_type(8))) short short8;   // 8 bf16 = 4 VGPR
typedef __attribute__((ext_vector_type(4))) float f32x4;    // MFMA acc
typedef __attribute__((ext_vector_type(4))) unsigned uint32x4;

__device__ __forceinline__ unsigned short f2bf(float x) {
    __hip_bfloat16 h = __float2bfloat16(x);
    return *reinterpret_cast<unsigned short*>(&h);
}
__device__ __forceinline__ unsigned int pack2bf(float a, float b) {
    __hip_bfloat162 h = __float22bfloat162_rn(float2{a, b});
    return *reinterpret_cast<unsigned int*>(&h);
}

// gfx950 register-pair lane swaps (both operands are read-modify-write).
// v_permlane32_swap_b32: vdst[32:63] <-> src[0:31]
// v_permlane16_swap_b32: rows 1,3 (lanes 16-31,48-63) of vdst <-> rows 0,2 of src
__device__ __forceinline__ void pl32_swap(unsigned& a, unsigned& b) {
    asm("v_permlane32_swap_b32 %0, %1" : "+v"(a), "+v"(b));
}
__device__ __forceinline__ void pl16_swap(unsigned& a, unsigned& b) {
    asm("v_permlane16_swap_b32 %0, %1" : "+v"(a), "+v"(b));
}

// async 16B global -> LDS (per-lane gptr; LDS dest must be wave-uniform-base + lane*16)
__device__ __forceinline__ void gl_lds16(const void* g, void* l) {
    __builtin_amdgcn_global_load_lds(
        (const __attribute__((address_space(1))) unsigned int*)g,
        (__attribute__((address_space(3))) unsigned int*)l,
        16, 0, 0);
}

// ---------------- prep: 4 weight transposes (z=0..3) + queries convert (z=4) ----------------
__global__ __launch_bounds__(256) void prep_kernel(const float* __restrict__ W0,
                                                   const float* __restrict__ W1,
                                                   const float* __restrict__ W2,
                                                   const float* __restrict__ W3,
                                                   const float* __restrict__ queries,
                                                   unsigned short* __restrict__ Wqkvt,
                                                   unsigned short* __restrict__ Wot,
                                                   unsigned short* __restrict__ qout)
{
    const int z = blockIdx.z;
    const int t = threadIdx.x;

    if (z == 4) {
        // bulk fp32 -> bf16 convert of queries
        const int nthr = 16 * 16 * 256;            // 65536
        int i = (blockIdx.y * 16 + blockIdx.x) * 256 + t;
        for (int it = 0; it < (BATCH * SEQ * DIM / 4) / nthr; it++, i += nthr) {
            float4 v = ((const float4*)queries)[i];
            ushort4 u;
            u.x = f2bf(v.x); u.y = f2bf(v.y); u.z = f2bf(v.z); u.w = f2bf(v.w);
            ((ushort4*)qout)[i] = u;
        }
        return;
    }

    __shared__ float Ts[64][65];
    const float* W = (z == 0) ? W0 : (z == 1) ? W1 : (z == 2) ? W2 : W3;
    unsigned short* Wt = (z == 3) ? Wot : (Wqkvt + (size_t)z * DIM * DIM);

    const int k0 = blockIdx.y * 64, n0 = blockIdx.x * 64;
    const int lr = t >> 2, lq = t & 3;

#pragma unroll
    for (int i = 0; i < 4; i++) {
        float4 v = *(const float4*)(W + (size_t)(k0 + lr) * DIM + n0 + (lq * 4 + i) * 4);
        Ts[lr][(lq * 4 + i) * 4 + 0] = v.x;
        Ts[lr][(lq * 4 + i) * 4 + 1] = v.y;
        Ts[lr][(lq * 4 + i) * 4 + 2] = v.z;
        Ts[lr][(lq * 4 + i) * 4 + 3] = v.w;
    }
    __syncthreads();
#pragma unroll
    for (int i = 0; i < 4; i++) {
        const int c = lq * 16 + i * 4;
        ushort4 u;
        u.x = f2bf(Ts[c + 0][lr]);
        u.y = f2bf(Ts[c + 1][lr]);
        u.z = f2bf(Ts[c + 2][lr]);
        u.w = f2bf(Ts[c + 3][lr]);
        *(ushort4*)(Wt + (size_t)(n0 + lr) * DIM + k0 + c) = u;
    }
}

// ---------------- fused QKV GEMM: [8192,1024] @ [3072,1024]^T ----------------
// sector 0: Qbf natural bf16, (acc+bq)*QSCALE
// sector 1: Kbf natural bf16, acc+bk
// sector 2: Vtb transposed-per-head: Vt[b][h][d][l], acc+bv
__global__ __launch_bounds__(256) void gemm_qkv(const unsigned short* __restrict__ A,
                                                const unsigned short* __restrict__ Bt,
                                                const float* __restrict__ bq,
                                                const float* __restrict__ bk,
                                                const float* __restrict__ bv,
                                                unsigned short* __restrict__ Qbf,
                                                unsigned short* __restrict__ Kbf,
                                                unsigned short* __restrict__ Vtb)
{
    __shared__ __attribute__((aligned(16))) unsigned short As[128 * 32];
    __shared__ __attribute__((aligned(16))) unsigned short Bs[128 * 32];

    const int tid = threadIdx.x;
    const int w = tid >> 6, lane = tid & 63;
    const int col = lane & 15, quad = lane >> 4;
    const int wm = (w >> 1) * 64, wn = (w & 1) * 64;
    const int m0 = blockIdx.y * 128, n0 = blockIdx.x * 128;

    f32x4 acc[4][4] = {};
    const int srow = tid >> 2, sc4 = tid & 3;

    for (int k0 = 0; k0 < DIM; k0 += 32) {
        __syncthreads();
#pragma unroll
        for (int it = 0; it < 2; it++) {
            gl_lds16(A  + (size_t)(m0 + srow + it * 64) * DIM + k0 + sc4 * 8,
                     (char*)As + w * 1024 + it * 4096);
            gl_lds16(Bt + (size_t)(n0 + srow + it * 64) * DIM + k0 + sc4 * 8,
                     (char*)Bs + w * 1024 + it * 4096);
        }
        __syncthreads();

        short8 af[4], bf[4];
#pragma unroll
        for (int mt = 0; mt < 4; mt++) af[mt] = *(short8*)&As[(wm + mt * 16 + col) * 32 + quad * 8];
#pragma unroll
        for (int nt = 0; nt < 4; nt++) bf[nt] = *(short8*)&Bs[(wn + nt * 16 + col) * 32 + quad * 8];

#pragma unroll
        for (int mt = 0; mt < 4; mt++)
#pragma unroll
            for (int nt = 0; nt < 4; nt++)
                acc[mt][nt] = __builtin_amdgcn_mfma_f32_16x16x32_bf16(af[mt], bf[nt], acc[mt][nt], 0, 0, 0);
    }

    const int sector = n0 >> 10;   // block never straddles (1024 % 128 == 0)
    const float* bias = (sector == 0) ? bq : (sector == 1) ? bk : bv;

#pragma unroll
    for (int nt = 0; nt < 4; nt++) {
        const int n = n0 + wn + nt * 16 + col;
        const int nloc = n - (sector << 10);
        const float bvv = bias[nloc];
#pragma unroll
        for (int mt = 0; mt < 4; mt++) {
            const int mbase = m0 + wm + mt * 16 + quad * 4;
            if (sector == 0) {
#pragma unroll
                for (int r = 0; r < 4; r++)
                    Qbf[(size_t)(mbase + r) * DIM + nloc] = f2bf((acc[mt][nt][r] + bvv) * QSCALE);
            } else if (sector == 1) {
#pragma unroll
                for (int r = 0; r < 4; r++)
                    Kbf[(size_t)(mbase + r) * DIM + nloc] = f2bf(acc[mt][nt][r] + bvv);
            } else {
                const int h = nloc >> 6, d = nloc & 63;
                const int b = mbase >> 11, l = mbase & 2047;
                ushort4 u;
                u.x = f2bf(acc[mt][nt][0] + bvv);
                u.y = f2bf(acc[mt][nt][1] + bvv);
                u.z = f2bf(acc[mt][nt][2] + bvv);
                u.w = f2bf(acc[mt][nt][3] + bvv);
                *(ushort4*)(Vtb + ((size_t)((b * NHEAD + h) * HDIM + d)) * SEQ + l) = u;
            }
        }
    }
}

// ---------------- out-proj GEMM: fp32 out = A @ Wot^T + bo + resid ----------------
__global__ __launch_bounds__(256) void gemm_out(const unsigned short* __restrict__ A,
                                                const unsigned short* __restrict__ Bt,
                                                const float* __restrict__ bias,
                                                const float* __restrict__ resid,
                                                float* __restrict__ Cout)
{
    __shared__ __attribute__((aligned(16))) unsigned short As[128 * 32];
    __shared__ __attribute__((aligned(16))) unsigned short Bs[128 * 32];

    const int tid = threadIdx.x;
    const int w = tid >> 6, lane = tid & 63;
    const int col = lane & 15, quad = lane >> 4;
    const int wm = (w >> 1) * 64, wn = (w & 1) * 64;
    const int m0 = blockIdx.y * 128, n0 = blockIdx.x * 128;

    f32x4 acc[4][4] = {};
    const int srow = tid >> 2, sc4 = tid & 3;

    for (int k0 = 0; k0 < DIM; k0 += 32) {
        __syncthreads();
#pragma unroll
        for (int it = 0; it < 2; it++) {
            gl_lds16(A  + (size_t)(m0 + srow + it * 64) * DIM + k0 + sc4 * 8,
                     (char*)As + w * 1024 + it * 4096);
            gl_lds16(Bt + (size_t)(n0 + srow + it * 64) * DIM + k0 + sc4 * 8,
                     (char*)Bs + w * 1024 + it * 4096);
        }
        __syncthreads();

        short8 af[4], bf[4];
#pragma unroll
        for (int mt = 0; mt < 4; mt++) af[mt] = *(short8*)&As[(wm + mt * 16 + col) * 32 + quad * 8];
#pragma unroll
        for (int nt = 0; nt < 4; nt++) bf[nt] = *(short8*)&Bs[(wn + nt * 16 + col) * 32 + quad * 8];

#pragma unroll
        for (int mt = 0; mt < 4; mt++)
#pragma unroll
            for (int nt = 0; nt < 4; nt++)
                acc[mt][nt] = __builtin_amdgcn_mfma_f32_16x16x32_bf16(af[mt], bf[nt], acc[mt][nt], 0, 0, 0);
    }

#pragma unroll
    for (int nt = 0; nt < 4; nt++) {
        const int n = n0 + wn + nt * 16 + col;
        const float bvv = bias[n];
#pragma unroll
        for (int mt = 0; mt < 4; mt++) {
            const int mbase = m0 + wm + mt * 16 + quad * 4;
#pragma unroll
            for (int r = 0; r < 4; r++) {
                const size_t off = (size_t)(mbase + r) * DIM + n;
                Cout[off] = acc[mt][nt][r] + bvv + resid[off];
            }
        }
    }
}

// ---------------- MFMA flash attention v19: v17 body, KVBLK=128 (resubmit) ----------------
// Round-12 run failed at the infra level (no counters); audit found no
// barrier divergence / OOB / hang mechanism, and the Round-4 precedent was
// an identical flake that passed on resubmission. Kernel unchanged.
// v17 (91.2us champion): wall ~2x max pipe (VALU 47, MFMA 31, LDS 27us) ->
// inter-phase overhead (32 barrier+drain events/block, full-block skew) is
// the remaining gap, not any single pipe.
// v19 = v17 with the K/V tile doubled to 128 keys, processed as FOUR 32-key
// groups with the v17 group body verbatim (per-g fused pf->den->PV so pf
// live-range stays 8 regs):
//  - barrier/drain events halve: 32 -> 16
//  - each DMA prefetch gets a 2x longer compute phase to land under
//  - per-key LDS/VALU/MFMA work unchanged; same verified row swizzle
//    (rows stay 64 halfs: K is [128][64]; V is 2 physical 64-key halves)
//  - LDS 64KB: free, grid 512 caps at 2 blocks/CU regardless
__global__ __launch_bounds__(512) void attn_mfma(const unsigned short* __restrict__ Qb,
                                                 const unsigned short* __restrict__ Kb,
                                                 const unsigned short* __restrict__ Vt,
                                                 unsigned short* __restrict__ Ob)
{
    __shared__ __attribute__((aligned(16))) unsigned short Ks[2 * 128 * 64];     // [buf][key][d'] swizzled
    __shared__ __attribute__((aligned(16))) unsigned short Vs[2 * 2 * 64 * 64];  // [buf][keyhalf][d][key'] swizzled

    const int tid = threadIdx.x;
    const int w = tid >> 6, lane = tid & 63;     // w = 0..7
    const int col = lane & 15, quad = lane >> 4;
    const int cs  = col & 7;            // read-side swizzle key (row&7 == col&7 for all frag rows)
    const int ca  = quad ^ cs;          // chunk holding halfs quad*8 .. +7      (keys/d 0..31)
    const int cb  = (quad ^ 4) ^ cs;    // chunk holding halfs quad*8+32 .. +39  (keys/d 32..63)

    const int bh  = blockIdx.x & 63;   // (b,h) fastest -> q-blocks of one head share an XCD
    const int qt_ = blockIdx.x >> 6;   // 0..7 (q-tile of 256)
    const int b   = bh >> 4;
    const int h   = bh & 15;

    const int q0 = qt_ * 256 + w * 32;   // 32 q-rows per wave

    // Q B-fragments (two 16-row tiles per wave)
    short8 qf[2][2];
#pragma unroll
    for (int qt = 0; qt < 2; qt++) {
        const size_t base = ((size_t)(b * SEQ) + q0 + qt * 16 + col) * DIM + h * HDIM + quad * 8;
        qf[qt][0] = *(const short8*)(Qb + base);
        qf[qt][1] = *(const short8*)(Qb + base + 32);
    }

    // ones A-fragment (row 0 = key-sum of P)
    short8 onesf;
    {
        const short v = (col == 0) ? (short)0x3F80 : (short)0;
        onesf = short8{v, v, v, v, v, v, v, v};
    }

    f32x4 o[4][2] = {};
    f32x4 od[2]   = {};

    const size_t kbase0 = ((size_t)(b * SEQ)) * DIM + h * HDIM;
    const size_t vbase0 = ((size_t)((b * NHEAD + h) * HDIM)) * SEQ;

    // DMA staging: 4 instrs per wave per 128-key tile (2 K row-blocks, 2 V halves).
    // Linear LDS dest, XOR-swizzled global source chunk (involution).
    const int lr  = lane >> 3;              // row-within-8 (== row&7)
    const int swc = (lane & 7) ^ lr;        // swizzled source chunk

    // prologue: DMA tile 0 into buf 0
#pragma unroll
    for (int it = 0; it < 2; it++) {
        const int row = it * 64 + w * 8 + lr;
        gl_lds16(Kb + kbase0 + (size_t)row * DIM + swc * 8,
                 (char*)Ks + it * 8192 + w * 1024);
    }
#pragma unroll
    for (int hv = 0; hv < 2; hv++) {
        const int row = w * 8 + lr;
        gl_lds16(Vt + vbase0 + (size_t)row * SEQ + hv * 64 + swc * 8,
                 (char*)Vs + hv * 8192 + w * 1024);
    }
    __syncthreads();

    for (int kt = 0; kt < SEQ / 128; kt++) {
        const int cur = kt & 1, nxt = cur ^ 1;
        const unsigned short* Ksb = Ks + cur * 8192;   // halfs (16 KB/buf)
        const unsigned short* Vsb = Vs + cur * 8192;   // halfs (16 KB/buf)

        // issue next tile's DMA now; latency hides under this tile's compute
        if (kt + 1 < SEQ / 128) {
#pragma unroll
            for (int it = 0; it < 2; it++) {
                const int row = it * 64 + w * 8 + lr;
                gl_lds16(Kb + kbase0 + (size_t)((kt + 1) * 128 + row) * DIM + swc * 8,
                         (char*)Ks + nxt * 16384 + it * 8192 + w * 1024);
            }
#pragma unroll
            for (int hv = 0; hv < 2; hv++) {
                const int row = w * 8 + lr;
                gl_lds16(Vt + vbase0 + (size_t)row * SEQ + (kt + 1) * 128 + hv * 64 + swc * 8,
                         (char*)Vs + nxt * 16384 + hv * 8192 + w * 1024);
            }
        }

        // four 32-key groups: S^T = K @ Q^T ; P = 2^S ; reshape; den; PV
#pragma unroll
        for (int g = 0; g < 4; g++) {
            short8 kfe0 = *(short8*)&Ksb[((g * 2 + 0) * 16 + col) * 64 + ca * 8];
            short8 kfe1 = *(short8*)&Ksb[((g * 2 + 0) * 16 + col) * 64 + cb * 8];
            short8 kfo0 = *(short8*)&Ksb[((g * 2 + 1) * 16 + col) * 64 + ca * 8];
            short8 kfo1 = *(short8*)&Ksb[((g * 2 + 1) * 16 + col) * 64 + cb * 8];

            short8 pf[2];
#pragma unroll
            for (int qt = 0; qt < 2; qt++) {
                f32x4 se = {};
                se = __builtin_amdgcn_mfma_f32_16x16x32_bf16(kfe0, qf[qt][0], se, 0, 0, 0);
                se = __builtin_amdgcn_mfma_f32_16x16x32_bf16(kfe1, qf[qt][1], se, 0, 0, 0);
                f32x4 so = {};
                so = __builtin_amdgcn_mfma_f32_16x16x32_bf16(kfo0, qf[qt][0], so, 0, 0, 0);
                so = __builtin_amdgcn_mfma_f32_16x16x32_bf16(kfo1, qf[qt][1], so, 0, 0, 0);

                unsigned a0 = pack2bf(__builtin_amdgcn_exp2f(se[0]), __builtin_amdgcn_exp2f(se[1]));
                unsigned b0 = pack2bf(__builtin_amdgcn_exp2f(se[2]), __builtin_amdgcn_exp2f(se[3]));
                unsigned a1 = pack2bf(__builtin_amdgcn_exp2f(so[0]), __builtin_amdgcn_exp2f(so[1]));
                unsigned b1 = pack2bf(__builtin_amdgcn_exp2f(so[2]), __builtin_amdgcn_exp2f(so[3]));

                pl32_swap(a0, a1);   // pair even/odd nt across lane halves
                pl32_swap(b0, b1);
                pl16_swap(a0, a1);   // quad exchange 0<->1, 2<->3
                pl16_swap(b0, b1);

                uint32x4 cv = {a0, b0, a1, b1};
                pf[qt] = __builtin_bit_cast(short8, cv);
            }

            __builtin_amdgcn_s_setprio(1);
            // denominator rows (ones A-fragment MFMA; this group's 32 keys)
#pragma unroll
            for (int qt = 0; qt < 2; qt++)
                od[qt] = __builtin_amdgcn_mfma_f32_16x16x32_bf16(onesf, pf[qt], od[qt], 0, 0, 0);

            // O^T += V^T[d][this group's keys] @ P^T (vf read once, reused both qt)
            const int hv = g >> 1;
            const int coff = (g & 1) ? cb : ca;
#pragma unroll
            for (int mt = 0; mt < 4; mt++) {
                short8 vf = *(short8*)&Vsb[hv * 4096 + (mt * 16 + col) * 64 + coff * 8];
#pragma unroll
                for (int qt = 0; qt < 2; qt++)
                    o[mt][qt] = __builtin_amdgcn_mfma_f32_16x16x32_bf16(vf, pf[qt], o[mt][qt], 0, 0, 0);
            }
            __builtin_amdgcn_s_setprio(0);
        }

        // drains vmcnt (next tile's DMA landed) + lgkmcnt (this tile's reads done)
        __syncthreads();
    }

    // denom for q=col lives in od[qt][0] on quad-0 lane #col; broadcast
#pragma unroll
    for (int qt = 0; qt < 2; qt++) {
        const float den = __shfl(od[qt][0], col);
        const float inv = 1.f / den;
        const size_t rowoff = ((size_t)(b * SEQ) + q0 + qt * 16 + col) * DIM + h * HDIM;
#pragma unroll
        for (int mt = 0; mt < 4; mt++) {
            ushort4 u;
            u.x = f2bf(o[mt][qt][0] * inv);
            u.y = f2bf(o[mt][qt][1] * inv);
            u.z = f2bf(o[mt][qt][2] * inv);
            u.w = f2bf(o[mt][qt][3] * inv);
            *(ushort4*)(Ob + rowoff + mt * 16 + quad * 4) = u;
        }
    }
}

// ---------------- LayerNorm (in-place on d_out) ----------------
__global__ __launch_bounds__(256) void layernorm_kernel(float* __restrict__ res,
                                                        const float* __restrict__ gamma,
                                                        const float* __restrict__ beta)
{
    const int tid = threadIdx.x;
    const int row = blockIdx.x;
    float4 xv = ((const float4*)(res + (size_t)row * DIM))[tid];

    float s  = xv.x + xv.y + xv.z + xv.w;
    float sq = xv.x * xv.x + xv.y * xv.y + xv.z * xv.z + xv.w * xv.w;
#pragma unroll
    for (int off = 32; off; off >>= 1) {
        s  += __shfl_xor(s, off);
        sq += __shfl_xor(sq, off);
    }
    __shared__ float sm[8];
    const int w = tid >> 6, lane = tid & 63;
    if (lane == 0) { sm[w] = s; sm[4 + w] = sq; }
    __syncthreads();
    const float st  = sm[0] + sm[1] + sm[2] + sm[3];
    const float sqt = sm[4] + sm[5] + sm[6] + sm[7];
    const float mu   = st * (1.f / DIM);
    const float var  = sqt * (1.f / DIM) - mu * mu;
    const float rstd = rsqrtf(var + EPS_LN);

    float4 g  = ((const float4*)gamma)[tid];
    float4 be = ((const float4*)beta)[tid];
    float4 o;
    o.x = (xv.x - mu) * rstd * g.x + be.x;
    o.y = (xv.y - mu) * rstd * g.y + be.y;
    o.z = (xv.z - mu) * rstd * g.z + be.z;
    o.w = (xv.w - mu) * rstd * g.w + be.w;
    ((float4*)(res + (size_t)row * DIM))[tid] = o;
}

// ---------------- launch ----------------
extern "C" void kernel_launch(void* const* d_in, const int* in_sizes, int n_in,
                              void* d_out, int out_size, void* d_ws, size_t ws_size,
                              hipStream_t stream)
{
    const float* queries = (const float*)d_in[0];
    const float* Wq = (const float*)d_in[1];
    const float* bq = (const float*)d_in[2];
    const float* Wk = (const float*)d_in[3];
    const float* bk = (const float*)d_in[4];
    const float* Wv = (const float*)d_in[5];
    const float* bv = (const float*)d_in[6];
    const float* Wo = (const float*)d_in[7];
    const float* bo = (const float*)d_in[8];
    const float* gamma = (const float*)d_in[9];
    const float* beta  = (const float*)d_in[10];
    float* outp = (float*)d_out;

    const int M = BATCH * SEQ;                    // 8192
    const size_t BUF = (size_t)M * DIM;
    const size_t WSZ = (size_t)DIM * DIM;

    unsigned short* w0  = (unsigned short*)d_ws;
    unsigned short* qin = w0;                     // bf16 queries; later: attention output
    unsigned short* Qbf = w0 + BUF;
    unsigned short* Kbf = w0 + 2 * BUF;
    unsigned short* Vtb = w0 + 3 * BUF;
    unsigned short* Wqkvt = w0 + 4 * BUF;         // [3072][1024]
    unsigned short* Wot   = Wqkvt + 3 * WSZ;
    unsigned short* Obf = qin;                    // reuse

    dim3 blk(256);

    // z=0..3: weight transposes; z=4: queries fp32->bf16
    dim3 pgrid(DIM / 64, DIM / 64, 5);
    prep_kernel<<<pgrid, blk, 0, stream>>>(Wq, Wk, Wv, Wo, queries, Wqkvt, Wot, qin);

    dim3 qkvgrid(3 * DIM / 128, M / 128);         // (24, 64) = 1536 blocks
    gemm_qkv<<<qkvgrid, blk, 0, stream>>>(qin, Wqkvt, bq, bk, bv, Qbf, Kbf, Vtb);

    // 512 blocks x 512 threads: swizzled decode (bh = idx & 63, qt = idx >> 6)
    attn_mfma<<<BATCH * NHEAD * (SEQ / 256), dim3(512), 0, stream>>>(Qbf, Kbf, Vtb, Obf);

    dim3 ogrid(DIM / 128, M / 128);               // (8, 64)
    gemm_out<<<ogrid, blk, 0, stream>>>(Obf, Wot, bo, queries, outp);

    layernorm_kernel<<<M, blk, 0, stream>>>(outp, gamma, beta);
}